// Round 4
// baseline (73.878 us; speedup 1.0000x reference)
//
#include <hip/hip_runtime.h>

#define NPIX 9216          // C*H*W = 1*96*96
#define NROWS (NPIX + 1)   // 9217 rows in zonotope
#define ROW4 (NPIX / 4)    // 2304 float4 per row
#define EPSV 0.1f

typedef float f32x4 __attribute__((ext_vector_type(4)));

// ---------------------------------------------------------------------------
// Kernel 1: pure zero-fill of rows 1..9216 (the error-term region).
// 9216 rows * 2304 f32x4 = 21,233,664 = 262,144 threads * 81 exactly.
// Branch-free, load-free, nontemporal dwordx4 stores -> memset-rate stores.
// Row 0 is NOT touched here (written by finish_kernel; disjoint).
// ---------------------------------------------------------------------------
__global__ __launch_bounds__(256) void fill_kernel(f32x4* __restrict__ out) {
    const int tid = blockIdx.x * 256 + threadIdx.x;   // 0 .. 262143
    const f32x4 z = {0.0f, 0.0f, 0.0f, 0.0f};
    f32x4* p = out + ROW4 + tid;   // skip row 0
#pragma unroll 9
    for (int it = 0; it < 81; ++it) {
        __builtin_nontemporal_store(z, p);
        p += 262144;               // consecutive threads stay contiguous
    }
}

// ---------------------------------------------------------------------------
// Kernel 2 (after fill): single block, 1024 threads.
//  - per-pixel err + cond, block-wide shuffle scan (stream compaction)
//  - scatter: out[slot*NPIX + pixel] = err  (~3.7K dword stores)
//  - row 0 = clipped bias, coalesced f32x4 stores
// Rows past the compacted count keep the fill's zeros.
// ---------------------------------------------------------------------------
__global__ __launch_bounds__(1024) void finish_kernel(const float* __restrict__ x,
                                                      float* __restrict__ out) {
    __shared__ int wsum[16];
    const int tid  = threadIdx.x;
    const int lane = tid & 63;
    const int wid  = tid >> 6;
    const int base = tid * 9;      // 9 contiguous pixels per thread

    float e_loc[9];
    int   c_loc[9];
    int   cnt = 0;
#pragma unroll
    for (int k = 0; k < 9; ++k) {
        const float xv     = x[base + k];
        const float r_low  = fmaxf(EPSV - xv, 0.0f) * 0.5f;
        const float r_high = fmaxf(xv - (1.0f - EPSV), 0.0f) * 0.5f;
        const float e      = EPSV - r_low - r_high;
        e_loc[k] = e;
        c_loc[k] = (e >= 0.0f) ? 1 : 0;
        cnt += c_loc[k];
    }

    // inclusive shuffle scan of per-thread counts within each wave
    int v = cnt;
#pragma unroll
    for (int off = 1; off < 64; off <<= 1) {
        const int t = __shfl_up(v, off, 64);
        if (lane >= off) v += t;
    }
    if (lane == 63) wsum[wid] = v;
    __syncthreads();

    int woff = 0;
#pragma unroll
    for (int w = 0; w < 16; ++w) woff += (w < wid) ? wsum[w] : 0;

    int slot = woff + v - cnt;     // exclusive prefix (0-based)
#pragma unroll
    for (int k = 0; k < 9; ++k) {
        if (c_loc[k]) {
            ++slot;                // 1-based compacted slot == output row
            out[(long long)slot * NPIX + (base + k)] = e_loc[k];
        }
    }

    // row 0: clipped bias, coalesced f32x4
    const f32x4* x4 = reinterpret_cast<const f32x4*>(x);
    f32x4* o4 = reinterpret_cast<f32x4*>(out);
#pragma unroll
    for (int it = 0; it < 3; ++it) {
        const int c4 = tid + it * 1024;
        if (c4 < ROW4) {
            const f32x4 xv = x4[c4];
            f32x4 o;
#pragma unroll
            for (int d = 0; d < 4; ++d) {
                const float vv = xv[d];
                o[d] = vv + fmaxf(EPSV - vv, 0.0f) * 0.5f
                          - fmaxf(vv - (1.0f - EPSV), 0.0f) * 0.5f;
            }
            o4[c4] = o;
        }
    }
}

extern "C" void kernel_launch(void* const* d_in, const int* in_sizes, int n_in,
                              void* d_out, int out_size, void* d_ws, size_t ws_size,
                              hipStream_t stream) {
    const float* x = (const float*)d_in[0];
    float* out = (float*)d_out;

    fill_kernel<<<1024, 256, 0, stream>>>((f32x4*)out);
    finish_kernel<<<1, 1024, 0, stream>>>(x, out);
}

// Round 5
// 72.975 us; speedup vs baseline: 1.0124x; 1.0124x over previous
//
#include <hip/hip_runtime.h>

#define NPIX 9216          // C*H*W = 1*96*96
#define NROWS (NPIX + 1)   // 9217 rows in zonotope
#define ROW4 (NPIX / 4)    // 2304 float4 per row
#define EPSV 0.1f

typedef float f32x4 __attribute__((ext_vector_type(4)));

// ---------------------------------------------------------------------------
// Kernel 1: pure zero-fill of rows 1..9216 (the error-term region).
// 9216 rows * 2304 f32x4 = 21,233,664 = 262,144 threads * 81 exactly.
// Branch-free, load-free, REGULAR dwordx4 stores (NT bypassed L2 and ran at
// ~4.9 TB/s in R3/R4; fillBufferAligned's regular stores sustain 6.7-7.1).
// Row 0 is NOT touched here (written by finish_kernel; disjoint).
// ---------------------------------------------------------------------------
__global__ __launch_bounds__(256) void fill_kernel(f32x4* __restrict__ out) {
    const int tid = blockIdx.x * 256 + threadIdx.x;   // 0 .. 262143
    const f32x4 z = {0.0f, 0.0f, 0.0f, 0.0f};
    f32x4* p = out + ROW4 + tid;   // skip row 0
#pragma unroll 9
    for (int it = 0; it < 81; ++it) {
        p[0] = z;
        p += 262144;               // consecutive threads stay contiguous
    }
}

// ---------------------------------------------------------------------------
// Kernel 2 (after fill): single block, 1024 threads.
//  - per-pixel err + cond, block-wide shuffle scan (stream compaction)
//  - scatter: out[slot*NPIX + pixel] = err  (~3.7K dword stores)
//  - row 0 = clipped bias, coalesced f32x4 stores
// Rows past the compacted count keep the fill's zeros.
// ---------------------------------------------------------------------------
__global__ __launch_bounds__(1024) void finish_kernel(const float* __restrict__ x,
                                                      float* __restrict__ out) {
    __shared__ int wsum[16];
    const int tid  = threadIdx.x;
    const int lane = tid & 63;
    const int wid  = tid >> 6;
    const int base = tid * 9;      // 9 contiguous pixels per thread

    float e_loc[9];
    int   c_loc[9];
    int   cnt = 0;
#pragma unroll
    for (int k = 0; k < 9; ++k) {
        const float xv     = x[base + k];
        const float r_low  = fmaxf(EPSV - xv, 0.0f) * 0.5f;
        const float r_high = fmaxf(xv - (1.0f - EPSV), 0.0f) * 0.5f;
        const float e      = EPSV - r_low - r_high;
        e_loc[k] = e;
        c_loc[k] = (e >= 0.0f) ? 1 : 0;
        cnt += c_loc[k];
    }

    // inclusive shuffle scan of per-thread counts within each wave
    int v = cnt;
#pragma unroll
    for (int off = 1; off < 64; off <<= 1) {
        const int t = __shfl_up(v, off, 64);
        if (lane >= off) v += t;
    }
    if (lane == 63) wsum[wid] = v;
    __syncthreads();

    int woff = 0;
#pragma unroll
    for (int w = 0; w < 16; ++w) woff += (w < wid) ? wsum[w] : 0;

    int slot = woff + v - cnt;     // exclusive prefix (0-based)
#pragma unroll
    for (int k = 0; k < 9; ++k) {
        if (c_loc[k]) {
            ++slot;                // 1-based compacted slot == output row
            out[(long long)slot * NPIX + (base + k)] = e_loc[k];
        }
    }

    // row 0: clipped bias, coalesced f32x4
    const f32x4* x4 = reinterpret_cast<const f32x4*>(x);
    f32x4* o4 = reinterpret_cast<f32x4*>(out);
#pragma unroll
    for (int it = 0; it < 3; ++it) {
        const int c4 = tid + it * 1024;
        if (c4 < ROW4) {
            const f32x4 xv = x4[c4];
            f32x4 o;
#pragma unroll
            for (int d = 0; d < 4; ++d) {
                const float vv = xv[d];
                o[d] = vv + fmaxf(EPSV - vv, 0.0f) * 0.5f
                          - fmaxf(vv - (1.0f - EPSV), 0.0f) * 0.5f;
            }
            o4[c4] = o;
        }
    }
}

extern "C" void kernel_launch(void* const* d_in, const int* in_sizes, int n_in,
                              void* d_out, int out_size, void* d_ws, size_t ws_size,
                              hipStream_t stream) {
    const float* x = (const float*)d_in[0];
    float* out = (float*)d_out;

    fill_kernel<<<1024, 256, 0, stream>>>((f32x4*)out);
    finish_kernel<<<1, 1024, 0, stream>>>(x, out);
}

// Round 6
// 67.866 us; speedup vs baseline: 1.0886x; 1.0753x over previous
//
#include <hip/hip_runtime.h>

#define NPIX 9216          // C*H*W = 1*96*96
#define NROWS (NPIX + 1)   // 9217 rows in zonotope
#define ROW4 (NPIX / 4)    // 2304 float4 per row
#define EPSV 0.1f

#define FILL_BLOCKS 2592   // 2592 * 256 threads * 32 iters = 21,233,664 f32x4 = rows 1..9216
#define ITERS 32

typedef float f32x4 __attribute__((ext_vector_type(4)));

// ---------------------------------------------------------------------------
// Kernel 1: zero-fill rows 1..9216 with fillBuffer-style contiguous 128 KB
// chunk per block (block b owns f32x4 [ROW4 + b*8192, +8192); thread t writes
// chunk + it*256 + t — wave-contiguous 1 KB bursts, block-contiguous pages).
// Block FILL_BLOCKS additionally writes row 0 = clipped bias (elementwise
// from x, independent of the scan). No loads in fill blocks, no branches in
// the hot loop.
// ---------------------------------------------------------------------------
__global__ __launch_bounds__(256) void fill_kernel(const float* __restrict__ x,
                                                   f32x4* __restrict__ out) {
    const int b   = blockIdx.x;
    const int tid = threadIdx.x;

    if (b < FILL_BLOCKS) {
        const f32x4 z = {0.0f, 0.0f, 0.0f, 0.0f};
        f32x4* p = out + ROW4 + (long long)b * (256 * ITERS) + tid;
#pragma unroll
        for (int it = 0; it < ITERS; ++it) {
            p[0] = z;
            p += 256;
        }
    } else {
        // bias row (row 0): out[0][c] = clip-shifted center
        const f32x4* x4 = reinterpret_cast<const f32x4*>(x);
#pragma unroll
        for (int it = 0; it < 9; ++it) {
            const int c4 = tid + it * 256;
            const f32x4 xv = x4[c4];
            f32x4 o;
#pragma unroll
            for (int d = 0; d < 4; ++d) {
                const float v = xv[d];
                o[d] = v + fmaxf(EPSV - v, 0.0f) * 0.5f
                         - fmaxf(v - (1.0f - EPSV), 0.0f) * 0.5f;
            }
            out[c4] = o;
        }
    }
}

// ---------------------------------------------------------------------------
// Kernel 2 (after fill): single block, 1024 threads. Scan + scatter ONLY.
//  - per-pixel err + cond, block-wide shuffle scan (stream compaction)
//  - scatter: out[slot*NPIX + pixel] = err  (~3.7K dword stores)
// Rows past the compacted count keep the fill's zeros.
// ---------------------------------------------------------------------------
__global__ __launch_bounds__(1024) void finish_kernel(const float* __restrict__ x,
                                                      float* __restrict__ out) {
    __shared__ int wsum[16];
    const int tid  = threadIdx.x;
    const int lane = tid & 63;
    const int wid  = tid >> 6;
    const int base = tid * 9;      // 9 contiguous pixels per thread

    float e_loc[9];
    int   c_loc[9];
    int   cnt = 0;
#pragma unroll
    for (int k = 0; k < 9; ++k) {
        const float xv     = x[base + k];
        const float r_low  = fmaxf(EPSV - xv, 0.0f) * 0.5f;
        const float r_high = fmaxf(xv - (1.0f - EPSV), 0.0f) * 0.5f;
        const float e      = EPSV - r_low - r_high;
        e_loc[k] = e;
        c_loc[k] = (e >= 0.0f) ? 1 : 0;
        cnt += c_loc[k];
    }

    // inclusive shuffle scan of per-thread counts within each wave
    int v = cnt;
#pragma unroll
    for (int off = 1; off < 64; off <<= 1) {
        const int t = __shfl_up(v, off, 64);
        if (lane >= off) v += t;
    }
    if (lane == 63) wsum[wid] = v;
    __syncthreads();

    int woff = 0;
#pragma unroll
    for (int w = 0; w < 16; ++w) woff += (w < wid) ? wsum[w] : 0;

    int slot = woff + v - cnt;     // exclusive prefix (0-based)
#pragma unroll
    for (int k = 0; k < 9; ++k) {
        if (c_loc[k]) {
            ++slot;                // 1-based compacted slot == output row
            out[(long long)slot * NPIX + (base + k)] = e_loc[k];
        }
    }
}

extern "C" void kernel_launch(void* const* d_in, const int* in_sizes, int n_in,
                              void* d_out, int out_size, void* d_ws, size_t ws_size,
                              hipStream_t stream) {
    const float* x = (const float*)d_in[0];
    float* out = (float*)d_out;

    fill_kernel<<<FILL_BLOCKS + 1, 256, 0, stream>>>(x, (f32x4*)out);
    finish_kernel<<<1, 1024, 0, stream>>>(x, out);
}